// Round 1
// baseline (680.402 us; speedup 1.0000x reference)
//
#include <hip/hip_runtime.h>
#include <stdint.h>

#define NB 4
#define SEQ 2048
#define DM 1024
#define NH 16
#define NDQK 20
#define NDV 64
#define DLQ 256
#define DLKV 128
#define MR (NB*SEQ)       // 8192 rows
#define NKV (NH*DLKV)     // 2048

typedef __attribute__((ext_vector_type(8))) short bf8;   // 8 bf16 (4 VGPR) MFMA A/B frag
typedef __attribute__((ext_vector_type(4))) float f4;    // MFMA C/D frag
typedef __attribute__((ext_vector_type(4))) short s4;

#define MFMA16(a,b,c) __builtin_amdgcn_mfma_f32_16x16x32_bf16(a, b, c, 0, 0, 0)

__device__ __forceinline__ short f2b(float f) {  // f32 -> bf16 RNE
  union { float f; unsigned u; } v; v.f = f;
  return (short)((v.u + 0x7FFFu + ((v.u >> 16) & 1u)) >> 16);
}

__device__ __forceinline__ void gld16(void* lds, const void* g) {
  __builtin_amdgcn_global_load_lds((const __attribute__((address_space(1))) void*)g,
                                   (__attribute__((address_space(3))) void*)lds, 16, 0, 0);
}

// ---------------- convert h / wq_a / wkv_a to bf16 ----------------
__global__ __launch_bounds__(256) void k_conv(const float* __restrict__ h,
    const float* __restrict__ wqa, const float* __restrict__ wkva,
    short* __restrict__ hb, short* __restrict__ wqab, short* __restrict__ wkvab) {
  const int NH4 = (MR*DM)/4, NQ4 = (DLQ*DM)/4, NK4 = (DLKV*DM)/4;
  int stride = gridDim.x * blockDim.x;
  for (int i = blockIdx.x*blockDim.x + threadIdx.x; i < NH4+NQ4+NK4; i += stride) {
    const float4* s; short* d; int o;
    if (i < NH4)            { s = (const float4*)h;    d = hb;     o = i; }
    else if (i < NH4+NQ4)   { s = (const float4*)wqa;  d = wqab;   o = i - NH4; }
    else                    { s = (const float4*)wkva; d = wkvab;  o = i - NH4 - NQ4; }
    float4 v = s[o];
    s4 r; r.x = f2b(v.x); r.y = f2b(v.y); r.z = f2b(v.z); r.w = f2b(v.w);
    *(s4*)(d + (size_t)o*4) = r;
  }
}

// ---------------- Wcomb[h*128+c][l] = scale*log2e * sum_q wq_b[h*20+q][l]*wkv_b[h][q][c] ----------------
__global__ __launch_bounds__(256) void k_wcomb(const float* __restrict__ wqbw,
    const float* __restrict__ wqbb, const float* __restrict__ wkvb,
    short* __restrict__ Wc, float* __restrict__ bc) {
  const float SC = 0.22360679774997896f * 1.4426950408889634f; // DQK^-0.5 * log2(e)
  int n = blockIdx.x, l = threadIdx.x;
  int hh = n >> 7, c = n & 127;
  float acc = 0.f, bacc = 0.f;
  for (int q = 0; q < NDQK; ++q) {
    float wv = wkvb[(hh*84 + q)*128 + c];
    acc  += wqbw[(hh*20 + q)*256 + l] * wv;
    bacc += wqbb[hh*20 + q] * wv;
  }
  Wc[(size_t)n*256 + l] = f2b(acc * SC);
  if (l == 0) bc[n] = bacc * SC;
}

// ---------------- W2[d][h*128+c] = sum_v wo[d][h*64+v]*wkv_b[h][20+v][c] ----------------
__global__ __launch_bounds__(256) void k_w2(const float* __restrict__ wo,
    const float* __restrict__ wkvb, short* __restrict__ W2) {
  int idx = blockIdx.x*256 + threadIdx.x;
  int d = idx >> 11, k = idx & 2047, hh = k >> 7, c = k & 127;
  float acc = 0.f;
  #pragma unroll 8
  for (int v = 0; v < NDV; ++v)
    acc += wo[d*1024 + hh*64 + v] * wkvb[(hh*84 + 20 + v)*128 + c];
  W2[idx] = f2b(acc);
}

// ---------------- fused latent projection + RMSnorm ----------------
// out[m][n] = RMS(A[m]·W[n]^T + bias)[n] * nw[n]  over n in [0,BN).  BM=32, BK=64.
template<int BN, bool WT>
__global__ __launch_bounds__(256) void k_proj_rms(const short* __restrict__ Ab,
    const short* __restrict__ Wb, const float* __restrict__ bias,
    const float* __restrict__ nw, short* __restrict__ outp, short* __restrict__ outT) {
  constexpr int WN = BN/4, NI = WN/16;
  __shared__ __align__(16) char As[32*128];
  __shared__ __align__(16) char Ws[BN*128];
  __shared__ float red[32][4];
  const int tid = threadIdx.x, l = tid & 63, w = tid >> 6;
  const int l15 = l & 15, l4 = l >> 4, l7 = l & 7, l3 = l >> 3;
  const int m0 = blockIdx.x * 32;
  f4 z = {0.f,0.f,0.f,0.f};
  f4 acc[2][NI];
  for (int mi=0;mi<2;mi++) for (int ni=0;ni<NI;ni++) acc[mi][ni] = z;
  for (int kt = 0; kt < DM/64; ++kt) {
    __syncthreads();
    { int row = w*8 + l3;   // stage A tile 32x64 (1 chunk/wave), pre-swizzled source
      gld16(As + w*1024 + l*16,
            (const char*)Ab + ((size_t)(m0+row)*DM + kt*64)*2 + ((l7 ^ (row&7))*16)); }
    #pragma unroll
    for (int i = 0; i < BN/32; ++i) {   // stage W tile BNx64
      int ci = w*(BN/32) + i, row = ci*8 + l3;
      gld16(Ws + ci*1024 + l*16,
            (const char*)Wb + ((size_t)row*DM + kt*64)*2 + ((l7 ^ (row&7))*16));
    }
    asm volatile("s_waitcnt vmcnt(0)" ::: "memory");
    __syncthreads();
    #pragma unroll
    for (int kk = 0; kk < 2; ++kk) {
      bf8 a[2], bb[NI];
      #pragma unroll
      for (int mi=0;mi<2;mi++) { int row = mi*16 + l15;
        a[mi] = *(const bf8*)(As + row*128 + ((kk*64 + l4*16) ^ ((row&7)<<4))); }
      #pragma unroll
      for (int ni=0;ni<NI;ni++) { int n = w*WN + ni*16 + l15;
        bb[ni] = *(const bf8*)(Ws + n*128 + ((kk*64 + l4*16) ^ ((n&7)<<4))); }
      #pragma unroll
      for (int mi=0;mi<2;mi++)
        #pragma unroll
        for (int ni=0;ni<NI;ni++) acc[mi][ni] = MFMA16(a[mi], bb[ni], acc[mi][ni]);
    }
  }
  float bn[NI], nwv[NI];
  #pragma unroll
  for (int ni=0;ni<NI;ni++) { int n = w*WN + ni*16 + l15; bn[ni] = bias[n]; nwv[ni] = nw[n]; }
  #pragma unroll
  for (int mi=0;mi<2;mi++) {
    f4 v = z;
    #pragma unroll
    for (int ni=0;ni<NI;ni++)
      #pragma unroll
      for (int r=0;r<4;r++) { acc[mi][ni][r] += bn[ni]; v[r] += acc[mi][ni][r]*acc[mi][ni][r]; }
    #pragma unroll
    for (int r=0;r<4;r++)
      for (int x=1;x<16;x<<=1) v[r] += __shfl_xor(v[r], x);
    if (l15 == 0) {
      #pragma unroll
      for (int r=0;r<4;r++) red[mi*16 + l4*4 + r][w] = v[r];
    }
  }
  __syncthreads();
  #pragma unroll
  for (int mi=0;mi<2;mi++) {
    float sc[4];
    #pragma unroll
    for (int r=0;r<4;r++) { int row = mi*16 + l4*4 + r;
      float t = red[row][0] + red[row][1] + red[row][2] + red[row][3];
      sc[r] = rsqrtf(t * (1.0f/BN) + 1e-6f); }
    #pragma unroll
    for (int ni=0;ni<NI;ni++) { int n = w*WN + ni*16 + l15;
      #pragma unroll
      for (int r=0;r<4;r++) {
        int m = m0 + mi*16 + l4*4 + r;
        short bv = f2b(acc[mi][ni][r] * sc[r] * nwv[ni]);
        outp[(size_t)m*BN + n] = bv;
        if (WT) { int bb2 = m >> 11, s = m & 2047;
                  outT[((size_t)bb2*DLKV + n)*SEQ + s] = bv; }
      }
    }
  }
}

// ---------------- GEMM C[m][n] = A[m]·W[n] (+bias): BM=BN=128, BK=64, 4 waves ----------------
template<bool BOUT>
__global__ __launch_bounds__(256) void k_gemm(const short* __restrict__ A,
    const short* __restrict__ W, const float* __restrict__ bias,
    void* __restrict__ outp, int N, int K) {
  __shared__ __align__(16) char As[128*128];
  __shared__ __align__(16) char Ws[128*128];
  const int tid = threadIdx.x, l = tid & 63, w = tid >> 6;
  const int l15 = l&15, l4 = l>>4, l7 = l&7, l3 = l>>3;
  const int wm = w >> 1, wn = w & 1;
  const int n0 = blockIdx.x * 128, m0 = blockIdx.y * 128;
  f4 z = {0.f,0.f,0.f,0.f};
  f4 acc[4][4];
  for (int mi=0;mi<4;mi++) for (int ni=0;ni<4;ni++) acc[mi][ni] = z;
  for (int kt = 0; kt < (K>>6); ++kt) {
    __syncthreads();
    #pragma unroll
    for (int i=0;i<4;i++) {
      int ci = w*4 + i, row = ci*8 + l3;
      gld16(As + ci*1024 + l*16,
            (const char*)A + ((size_t)(m0+row)*K + kt*64)*2 + ((l7^(row&7))*16));
      gld16(Ws + ci*1024 + l*16,
            (const char*)W + ((size_t)(n0+row)*K + kt*64)*2 + ((l7^(row&7))*16));
    }
    asm volatile("s_waitcnt vmcnt(0)" ::: "memory");
    __syncthreads();
    #pragma unroll
    for (int kk=0;kk<2;kk++) {
      bf8 a[4], bb[4];
      #pragma unroll
      for (int mi=0;mi<4;mi++) { int row = wm*64+mi*16+l15;
        a[mi] = *(const bf8*)(As + row*128 + ((kk*64+l4*16)^((row&7)<<4))); }
      #pragma unroll
      for (int ni=0;ni<4;ni++) { int row = wn*64+ni*16+l15;
        bb[ni] = *(const bf8*)(Ws + row*128 + ((kk*64+l4*16)^((row&7)<<4))); }
      #pragma unroll
      for (int mi=0;mi<4;mi++)
        #pragma unroll
        for (int ni=0;ni<4;ni++) acc[mi][ni] = MFMA16(a[mi], bb[ni], acc[mi][ni]);
    }
  }
  #pragma unroll
  for (int ni=0;ni<4;ni++) {
    int n = n0 + wn*64 + ni*16 + l15;
    float bn = bias[n];
    #pragma unroll
    for (int mi=0;mi<4;mi++)
      #pragma unroll
      for (int r=0;r<4;r++) {
        int m = m0 + wm*64 + mi*16 + l4*4 + r;
        float val = acc[mi][ni][r] + bn;
        if (BOUT) ((short*)outp)[(size_t)m*N + n] = f2b(val);
        else      ((float*)outp)[(size_t)m*N + n] = val;
      }
  }
}

// ---------------- flash attention over latent space; D=128, QTILE=128 (4 waves x 32), KVTILE=64 ----------------
__global__ __launch_bounds__(256) void k_flash(const short* __restrict__ qkv,
    const short* __restrict__ kvn, const short* __restrict__ kvnT,
    short* __restrict__ vlat) {
  __shared__ __align__(16) char Ks[64*256];    // [t][c] bf16, xor-swizzled
  __shared__ __align__(16) char VTs[128*128];  // [c][t] bf16, xor-swizzled
  __shared__ __align__(16) short Pl[4*32*72];  // per-wave P, stride 72 (144B)
  const int tid = threadIdx.x, l = tid&63, w = tid>>6;
  const int l15 = l&15, l4 = l>>4, l7 = l&7, l3 = l>>3;
  const int qt = blockIdx.x, hh = blockIdx.y, b = blockIdx.z;
  const int qw = qt*128 + w*32;                 // wave's first q row (in-batch)
  const size_t rowbase = (size_t)(b*SEQ + qw);
  bf8 qf[2][4];                                  // Q held in registers
  #pragma unroll
  for (int mi=0;mi<2;mi++)
    #pragma unroll
    for (int kk=0;kk<4;kk++)
      qf[mi][kk] = *(const bf8*)(qkv + (rowbase + mi*16 + l15)*NKV + hh*128 + kk*32 + l4*8);
  f4 z = {0.f,0.f,0.f,0.f};
  f4 acc[2][8]; float mr[2][4], lr[2][4];
  for (int mi=0;mi<2;mi++) { for (int cf=0;cf<8;cf++) acc[mi][cf] = z;
    for (int r=0;r<4;r++) { mr[mi][r] = -3.0e38f; lr[mi][r] = 0.f; } }
  const int nt = qt*2 + 2;
  for (int it = 0; it < nt; ++it) {
    const int t0 = it*64;
    __syncthreads();
    #pragma unroll
    for (int i=0;i<4;i++) {  // stage K tile [64][128] bf16 (256B rows)
      int ci = w*4+i, tr = ci*4 + l4;
      gld16(Ks + ci*1024 + l*16,
            (const char*)kvn + ((size_t)(b*SEQ + t0 + tr)*DLKV)*2 + ((l15 ^ (tr&7))*16));
    }
    #pragma unroll
    for (int i=0;i<4;i++) {  // stage V^T tile [128][64] bf16 (128B rows)
      int ci = w*4+i, c = ci*8 + l3;
      gld16(VTs + ci*1024 + l*16,
            (const char*)kvnT + (((size_t)(b*DLKV + c)*SEQ) + t0)*2 + ((l7 ^ (c&7))*16));
    }
    asm volatile("s_waitcnt vmcnt(0)" ::: "memory");
    __syncthreads();
    if (t0 <= qw + 31) {
      f4 sc[2][4];
      for (int mi=0;mi<2;mi++) for (int tf=0;tf<4;tf++) sc[mi][tf] = z;
      #pragma unroll
      for (int kk=0;kk<4;kk++) {  // scores = Q·K^T (log2-domain, pre-scaled)
        bf8 bk[4];
        #pragma unroll
        for (int tf=0;tf<4;tf++) { int t = tf*16 + l15;
          bk[tf] = *(const bf8*)(Ks + t*256 + ((kk*64 + l4*16) ^ ((t&7)<<4))); }
        #pragma unroll
        for (int mi=0;mi<2;mi++)
          #pragma unroll
          for (int tf=0;tf<4;tf++) sc[mi][tf] = MFMA16(qf[mi][kk], bk[tf], sc[mi][tf]);
      }
      if (t0 + 63 > qw) {  // diagonal tile: causal mask
        #pragma unroll
        for (int mi=0;mi<2;mi++)
          #pragma unroll
          for (int tf=0;tf<4;tf++)
            #pragma unroll
            for (int r=0;r<4;r++) {
              int qg = qw + mi*16 + l4*4 + r, tg = t0 + tf*16 + l15;
              if (tg > qg) sc[mi][tf][r] = -3.0e38f;
            }
      }
      #pragma unroll
      for (int mi=0;mi<2;mi++) {  // online softmax
        float mn[4], al[4];
        #pragma unroll
        for (int r=0;r<4;r++) {
          float v = fmaxf(fmaxf(sc[mi][0][r], sc[mi][1][r]), fmaxf(sc[mi][2][r], sc[mi][3][r]));
          for (int x=1;x<16;x<<=1) v = fmaxf(v, __shfl_xor(v, x));
          float m2 = fmaxf(mr[mi][r], v);
          al[r] = exp2f(mr[mi][r] - m2);
          mr[mi][r] = m2; mn[r] = m2;
        }
        float rs[4] = {0.f,0.f,0.f,0.f};
        #pragma unroll
        for (int tf=0;tf<4;tf++)
          #pragma unroll
          for (int r=0;r<4;r++) {
            float p = exp2f(sc[mi][tf][r] - mn[r]);
            sc[mi][tf][r] = p; rs[r] += p;
          }
        #pragma unroll
        for (int r=0;r<4;r++) {
          float v = rs[r];
          for (int x=1;x<16;x<<=1) v += __shfl_xor(v, x);
          lr[mi][r] = lr[mi][r]*al[r] + v;
        }
        #pragma unroll
        for (int cf=0;cf<8;cf++)
          #pragma unroll
          for (int r=0;r<4;r++) acc[mi][cf][r] *= al[r];
        #pragma unroll
        for (int tf=0;tf<4;tf++)
          #pragma unroll
          for (int r=0;r<4;r++)
            Pl[(w*32 + mi*16 + l4*4 + r)*72 + tf*16 + l15] = f2b(sc[mi][tf][r]);
      }
      #pragma unroll
      for (int kk=0;kk<2;kk++) {  // PV: acc += P·V  (V^T as B operand)
        bf8 pa[2];
        #pragma unroll
        for (int mi=0;mi<2;mi++)
          pa[mi] = *(const bf8*)(Pl + (w*32 + mi*16 + l15)*72 + kk*32 + l4*8);
        #pragma unroll
        for (int cf=0;cf<8;cf++) {
          int c = cf*16 + l15;
          bf8 bv = *(const bf8*)(VTs + c*128 + ((kk*64 + l4*16) ^ ((c&7)<<4)));
          #pragma unroll
          for (int mi=0;mi<2;mi++) acc[mi][cf] = MFMA16(pa[mi], bv, acc[mi][cf]);
        }
      }
    }
  }
  #pragma unroll
  for (int mi=0;mi<2;mi++) {
    float inv[4];
    #pragma unroll
    for (int r=0;r<4;r++) inv[r] = 1.0f / lr[mi][r];
    #pragma unroll
    for (int cf=0;cf<8;cf++)
      #pragma unroll
      for (int r=0;r<4;r++) {
        size_t m = rowbase + mi*16 + l4*4 + r;
        vlat[m*NKV + hh*128 + cf*16 + l15] = f2b(acc[mi][cf][r] * inv[r]);
      }
  }
}

extern "C" void kernel_launch(void* const* d_in, const int* in_sizes, int n_in,
                              void* d_out, int out_size, void* d_ws, size_t ws_size,
                              hipStream_t stream) {
  const float* h     = (const float*)d_in[0];
  const float* wqaw  = (const float*)d_in[2];
  const float* wqa_b = (const float*)d_in[3];
  const float* qnw   = (const float*)d_in[4];
  const float* wqbw  = (const float*)d_in[5];
  const float* wqbb  = (const float*)d_in[6];
  const float* wkvaw = (const float*)d_in[7];
  const float* wkva_b= (const float*)d_in[8];
  const float* kvnw  = (const float*)d_in[9];
  const float* wkvb  = (const float*)d_in[10];
  const float* wow   = (const float*)d_in[11];
  const float* wob   = (const float*)d_in[12];

  char* ws = (char*)d_ws;
  size_t off = 0;
  auto alloc = [&](size_t bytes) { char* p = ws + off; off += (bytes + 255) & ~(size_t)255; return p; };
  short* hb     = (short*)alloc((size_t)MR*DM*2);
  short* wqab16 = (short*)alloc((size_t)DLQ*DM*2);
  short* wkvab16= (short*)alloc((size_t)DLKV*DM*2);
  short* qlat   = (short*)alloc((size_t)MR*DLQ*2);
  short* kvnb   = (short*)alloc((size_t)MR*DLKV*2);
  short* kvnT   = (short*)alloc((size_t)MR*DLKV*2);
  short* Wc     = (short*)alloc((size_t)NKV*DLQ*2);
  float* bc     = (float*)alloc((size_t)NKV*4);
  short* qkv    = (short*)alloc((size_t)MR*NKV*2);
  short* vlat   = (short*)alloc((size_t)MR*NKV*2);
  short* W2     = (short*)alloc((size_t)DM*NKV*2);

  k_conv<<<2048, 256, 0, stream>>>(h, wqaw, wkvaw, hb, wqab16, wkvab16);
  k_wcomb<<<NKV, 256, 0, stream>>>(wqbw, wqbb, wkvb, Wc, bc);
  k_w2<<<(DM*NKV)/256, 256, 0, stream>>>(wow, wkvb, W2);
  k_proj_rms<DLQ,  false><<<MR/32, 256, 0, stream>>>(hb, wqab16,  wqa_b,  qnw,  qlat, nullptr);
  k_proj_rms<DLKV, true ><<<MR/32, 256, 0, stream>>>(hb, wkvab16, wkva_b, kvnw, kvnb, kvnT);
  k_gemm<true ><<<dim3(NKV/128, MR/128), 256, 0, stream>>>(qlat, Wc, bc, qkv, NKV, DLQ);
  k_flash<<<dim3(SEQ/128, NH, NB), 256, 0, stream>>>(qkv, kvnb, kvnT, vlat);
  k_gemm<false><<<dim3(DM/128, MR/128), 256, 0, stream>>>(vlat, W2, wob, d_out, DM, NKV);
}

// Round 2
// 497.841 us; speedup vs baseline: 1.3667x; 1.3667x over previous
//
#include <hip/hip_runtime.h>
#include <stdint.h>

#define NB 4
#define SEQ 2048
#define DM 1024
#define NH 16
#define NDQK 20
#define NDV 64
#define DLQ 256
#define DLKV 128
#define MR (NB*SEQ)       // 8192 rows
#define NKV (NH*DLKV)     // 2048

typedef __attribute__((ext_vector_type(8))) short bf8;   // 8 bf16 (4 VGPR) MFMA A/B frag
typedef __attribute__((ext_vector_type(4))) float f4;    // MFMA C/D frag
typedef __attribute__((ext_vector_type(4))) short s4;

#define MFMA16(a,b,c) __builtin_amdgcn_mfma_f32_16x16x32_bf16(a, b, c, 0, 0, 0)

__device__ __forceinline__ short f2b(float f) {  // f32 -> bf16 RNE
  union { float f; unsigned u; } v; v.f = f;
  return (short)((v.u + 0x7FFFu + ((v.u >> 16) & 1u)) >> 16);
}

__device__ __forceinline__ void gld16(void* lds, const void* g) {
  __builtin_amdgcn_global_load_lds((const __attribute__((address_space(1))) void*)g,
                                   (__attribute__((address_space(3))) void*)lds, 16, 0, 0);
}

// ---------------- convert h / wq_a / wkv_a to bf16 ----------------
__global__ __launch_bounds__(256) void k_conv(const float* __restrict__ h,
    const float* __restrict__ wqa, const float* __restrict__ wkva,
    short* __restrict__ hb, short* __restrict__ wqab, short* __restrict__ wkvab) {
  const int NH4 = (MR*DM)/4, NQ4 = (DLQ*DM)/4, NK4 = (DLKV*DM)/4;
  int stride = gridDim.x * blockDim.x;
  for (int i = blockIdx.x*blockDim.x + threadIdx.x; i < NH4+NQ4+NK4; i += stride) {
    const float4* s; short* d; int o;
    if (i < NH4)            { s = (const float4*)h;    d = hb;     o = i; }
    else if (i < NH4+NQ4)   { s = (const float4*)wqa;  d = wqab;   o = i - NH4; }
    else                    { s = (const float4*)wkva; d = wkvab;  o = i - NH4 - NQ4; }
    float4 v = s[o];
    s4 r; r.x = f2b(v.x); r.y = f2b(v.y); r.z = f2b(v.z); r.w = f2b(v.w);
    *(s4*)(d + (size_t)o*4) = r;
  }
}

// ---------------- Wcomb[h*128+c][l] = scale*log2e * sum_q wq_b[h*20+q][l]*wkv_b[h][q][c] ----------------
__global__ __launch_bounds__(256) void k_wcomb(const float* __restrict__ wqbw,
    const float* __restrict__ wqbb, const float* __restrict__ wkvb,
    short* __restrict__ Wc, float* __restrict__ bc) {
  const float SC = 0.22360679774997896f * 1.4426950408889634f; // DQK^-0.5 * log2(e)
  int n = blockIdx.x, l = threadIdx.x;
  int hh = n >> 7, c = n & 127;
  float acc = 0.f, bacc = 0.f;
  for (int q = 0; q < NDQK; ++q) {
    float wv = wkvb[(hh*84 + q)*128 + c];
    acc  += wqbw[(hh*20 + q)*256 + l] * wv;
    bacc += wqbb[hh*20 + q] * wv;
  }
  Wc[(size_t)n*256 + l] = f2b(acc * SC);
  if (l == 0) bc[n] = bacc * SC;
}

// ---------------- W2[d][h*128+c] = sum_v wo[d][h*64+v]*wkv_b[h][20+v][c] ----------------
__global__ __launch_bounds__(256) void k_w2(const float* __restrict__ wo,
    const float* __restrict__ wkvb, short* __restrict__ W2) {
  int idx = blockIdx.x*256 + threadIdx.x;
  int d = idx >> 11, k = idx & 2047, hh = k >> 7, c = k & 127;
  float acc = 0.f;
  #pragma unroll 8
  for (int v = 0; v < NDV; ++v)
    acc += wo[d*1024 + hh*64 + v] * wkvb[(hh*84 + 20 + v)*128 + c];
  W2[idx] = f2b(acc);
}

// ---------------- fused latent projection + RMSnorm ----------------
template<int BN, bool WT>
__global__ __launch_bounds__(256) void k_proj_rms(const short* __restrict__ Ab,
    const short* __restrict__ Wb, const float* __restrict__ bias,
    const float* __restrict__ nw, short* __restrict__ outp, short* __restrict__ outT) {
  constexpr int WN = BN/4, NI = WN/16;
  __shared__ __align__(16) char As[32*128];
  __shared__ __align__(16) char Ws[BN*128];
  __shared__ float red[32][4];
  const int tid = threadIdx.x, l = tid & 63, w = tid >> 6;
  const int l15 = l & 15, l4 = l >> 4, l7 = l & 7, l3 = l >> 3;
  const int m0 = blockIdx.x * 32;
  f4 z = {0.f,0.f,0.f,0.f};
  f4 acc[2][NI];
  for (int mi=0;mi<2;mi++) for (int ni=0;ni<NI;ni++) acc[mi][ni] = z;
  for (int kt = 0; kt < DM/64; ++kt) {
    __syncthreads();
    { int row = w*8 + l3;
      gld16(As + w*1024 + l*16,
            (const char*)Ab + ((size_t)(m0+row)*DM + kt*64)*2 + ((l7 ^ (row&7))*16)); }
    #pragma unroll
    for (int i = 0; i < BN/32; ++i) {
      int ci = w*(BN/32) + i, row = ci*8 + l3;
      gld16(Ws + ci*1024 + l*16,
            (const char*)Wb + ((size_t)row*DM + kt*64)*2 + ((l7 ^ (row&7))*16));
    }
    asm volatile("s_waitcnt vmcnt(0)" ::: "memory");
    __syncthreads();
    #pragma unroll
    for (int kk = 0; kk < 2; ++kk) {
      bf8 a[2], bb[NI];
      #pragma unroll
      for (int mi=0;mi<2;mi++) { int row = mi*16 + l15;
        a[mi] = *(const bf8*)(As + row*128 + ((kk*64 + l4*16) ^ ((row&7)<<4))); }
      #pragma unroll
      for (int ni=0;ni<NI;ni++) { int n = w*WN + ni*16 + l15;
        bb[ni] = *(const bf8*)(Ws + n*128 + ((kk*64 + l4*16) ^ ((n&7)<<4))); }
      #pragma unroll
      for (int mi=0;mi<2;mi++)
        #pragma unroll
        for (int ni=0;ni<NI;ni++) acc[mi][ni] = MFMA16(a[mi], bb[ni], acc[mi][ni]);
    }
  }
  float bn[NI], nwv[NI];
  #pragma unroll
  for (int ni=0;ni<NI;ni++) { int n = w*WN + ni*16 + l15; bn[ni] = bias[n]; nwv[ni] = nw[n]; }
  #pragma unroll
  for (int mi=0;mi<2;mi++) {
    f4 v = z;
    #pragma unroll
    for (int ni=0;ni<NI;ni++)
      #pragma unroll
      for (int r=0;r<4;r++) { acc[mi][ni][r] += bn[ni]; v[r] += acc[mi][ni][r]*acc[mi][ni][r]; }
    #pragma unroll
    for (int r=0;r<4;r++)
      for (int x=1;x<16;x<<=1) v[r] += __shfl_xor(v[r], x);
    if (l15 == 0) {
      #pragma unroll
      for (int r=0;r<4;r++) red[mi*16 + l4*4 + r][w] = v[r];
    }
  }
  __syncthreads();
  #pragma unroll
  for (int mi=0;mi<2;mi++) {
    float sc[4];
    #pragma unroll
    for (int r=0;r<4;r++) { int row = mi*16 + l4*4 + r;
      float t = red[row][0] + red[row][1] + red[row][2] + red[row][3];
      sc[r] = rsqrtf(t * (1.0f/BN) + 1e-6f); }
    #pragma unroll
    for (int ni=0;ni<NI;ni++) { int n = w*WN + ni*16 + l15;
      #pragma unroll
      for (int r=0;r<4;r++) {
        int m = m0 + mi*16 + l4*4 + r;
        short bv = f2b(acc[mi][ni][r] * sc[r] * nwv[ni]);
        outp[(size_t)m*BN + n] = bv;
        if (WT) { int bb2 = m >> 11, s = m & 2047;
                  outT[((size_t)bb2*DLKV + n)*SEQ + s] = bv; }
      }
    }
  }
}

// ---------------- GEMM C[m][n] = A[m]·W[n] (+bias): BM=BN=128, BK=64, 4 waves ----------------
template<bool BOUT>
__global__ __launch_bounds__(256) void k_gemm(const short* __restrict__ A,
    const short* __restrict__ W, const float* __restrict__ bias,
    void* __restrict__ outp, int N, int K) {
  __shared__ __align__(16) char As[128*128];
  __shared__ __align__(16) char Ws[128*128];
  const int tid = threadIdx.x, l = tid & 63, w = tid >> 6;
  const int l15 = l&15, l4 = l>>4, l7 = l&7, l3 = l>>3;
  const int wm = w >> 1, wn = w & 1;
  const int n0 = blockIdx.x * 128, m0 = blockIdx.y * 128;
  f4 z = {0.f,0.f,0.f,0.f};
  f4 acc[4][4];
  for (int mi=0;mi<4;mi++) for (int ni=0;ni<4;ni++) acc[mi][ni] = z;
  for (int kt = 0; kt < (K>>6); ++kt) {
    __syncthreads();
    #pragma unroll
    for (int i=0;i<4;i++) {
      int ci = w*4 + i, row = ci*8 + l3;
      gld16(As + ci*1024 + l*16,
            (const char*)A + ((size_t)(m0+row)*K + kt*64)*2 + ((l7^(row&7))*16));
      gld16(Ws + ci*1024 + l*16,
            (const char*)W + ((size_t)(n0+row)*K + kt*64)*2 + ((l7^(row&7))*16));
    }
    asm volatile("s_waitcnt vmcnt(0)" ::: "memory");
    __syncthreads();
    #pragma unroll
    for (int kk=0;kk<2;kk++) {
      bf8 a[4], bb[4];
      #pragma unroll
      for (int mi=0;mi<4;mi++) { int row = wm*64+mi*16+l15;
        a[mi] = *(const bf8*)(As + row*128 + ((kk*64+l4*16)^((row&7)<<4))); }
      #pragma unroll
      for (int ni=0;ni<4;ni++) { int row = wn*64+ni*16+l15;
        bb[ni] = *(const bf8*)(Ws + row*128 + ((kk*64+l4*16)^((row&7)<<4))); }
      #pragma unroll
      for (int mi=0;mi<4;mi++)
        #pragma unroll
        for (int ni=0;ni<4;ni++) acc[mi][ni] = MFMA16(a[mi], bb[ni], acc[mi][ni]);
    }
  }
  #pragma unroll
  for (int ni=0;ni<4;ni++) {
    int n = n0 + wn*64 + ni*16 + l15;
    float bn = bias[n];
    #pragma unroll
    for (int mi=0;mi<4;mi++)
      #pragma unroll
      for (int r=0;r<4;r++) {
        int m = m0 + wm*64 + mi*16 + l4*4 + r;
        float val = acc[mi][ni][r] + bn;
        if (BOUT) ((short*)outp)[(size_t)m*N + n] = f2b(val);
        else      ((float*)outp)[(size_t)m*N + n] = val;
      }
  }
}

// ---------------- flash attention, barrier-free: 1 wave = 32 q rows, K/V direct from L2 ----------------
// grid: x = h + 16*b (64), y = heavy-first q-block (64). Block = 64 threads (1 wave).
__global__ __launch_bounds__(64, 2) void k_flash(const short* __restrict__ qkv,
    const short* __restrict__ kvn, const short* __restrict__ kvnT,
    short* __restrict__ vlat) {
  __shared__ __align__(16) short Pl[32*72];   // per-wave P, stride 72 shorts (144B)
  const int l = threadIdx.x & 63;
  const int l15 = l & 15, l4 = l >> 4;
  const int hb = blockIdx.x, hh = hb & 15, b = hb >> 4;
  const int qb = 63 - (int)blockIdx.y;        // heavy blocks dispatch first
  const int qw = qb * 32;
  const size_t rowbase = (size_t)(b*SEQ + qw);
  const short* Kbase = kvn  + (size_t)b*SEQ*DLKV;   // [t][c]
  const short* Vbase = kvnT + (size_t)b*DLKV*SEQ;   // [c][t]

  bf8 qf[2][4];                                // Q in registers (32 q rows x 128 c)
  #pragma unroll
  for (int mi=0;mi<2;mi++)
    #pragma unroll
    for (int kk=0;kk<4;kk++)
      qf[mi][kk] = *(const bf8*)(qkv + (rowbase + mi*16 + l15)*NKV + hh*128 + kk*32 + l4*8);

  f4 z = {0.f,0.f,0.f,0.f};
  f4 acc[2][8], sums[2]; float mr[2][4];
  #pragma unroll
  for (int mi=0;mi<2;mi++) { sums[mi] = z;
    #pragma unroll
    for (int cf=0;cf<8;cf++) acc[mi][cf] = z;
    #pragma unroll
    for (int r=0;r<4;r++) mr[mi][r] = -3.0e38f; }

  const short ONE = 0x3F80;                    // bf16 1.0
  bf8 ones; 
  #pragma unroll
  for (int j=0;j<8;j++) ones[j] = ONE;

  const int nt = ((qw + 31) >> 6) + 1;
  for (int it = 0; it < nt; ++it) {
    const int t0 = it*64;
    // ---- scores = Q·K^T (exp2 domain, pre-scaled) ----
    f4 sc[2][4];
    #pragma unroll
    for (int mi=0;mi<2;mi++)
      #pragma unroll
      for (int tf=0;tf<4;tf++) sc[mi][tf] = z;
    #pragma unroll
    for (int kk=0;kk<4;kk++) {
      bf8 bk[4];
      #pragma unroll
      for (int tf=0;tf<4;tf++)
        bk[tf] = *(const bf8*)(Kbase + (size_t)(t0 + tf*16 + l15)*DLKV + kk*32 + l4*8);
      #pragma unroll
      for (int mi=0;mi<2;mi++)
        #pragma unroll
        for (int tf=0;tf<4;tf++) sc[mi][tf] = MFMA16(qf[mi][kk], bk[tf], sc[mi][tf]);
    }
    if (t0 + 63 > qw) {   // diagonal tile: causal mask
      #pragma unroll
      for (int mi=0;mi<2;mi++)
        #pragma unroll
        for (int tf=0;tf<4;tf++)
          #pragma unroll
          for (int r=0;r<4;r++) {
            int qg = qw + mi*16 + l4*4 + r, tg = t0 + tf*16 + l15;
            if (tg > qg) sc[mi][tf][r] = -3.0e38f;
          }
    }
    // ---- online softmax (max via shfl; sum via ones-MFMA later) ----
    #pragma unroll
    for (int mi=0;mi<2;mi++) {
      float mn[4], al[4];
      #pragma unroll
      for (int r=0;r<4;r++) {
        float v = fmaxf(fmaxf(sc[mi][0][r], sc[mi][1][r]), fmaxf(sc[mi][2][r], sc[mi][3][r]));
        for (int x=1;x<16;x<<=1) v = fmaxf(v, __shfl_xor(v, x));
        float m2 = fmaxf(mr[mi][r], v);
        al[r] = exp2f(mr[mi][r] - m2);
        mr[mi][r] = m2; mn[r] = m2;
      }
      #pragma unroll
      for (int r=0;r<4;r++) { sums[mi][r] *= al[r];
        #pragma unroll
        for (int cf=0;cf<8;cf++) acc[mi][cf][r] *= al[r]; }
      #pragma unroll
      for (int tf=0;tf<4;tf++)
        #pragma unroll
        for (int r=0;r<4;r++)
          Pl[(mi*16 + l4*4 + r)*72 + tf*16 + l15] = f2b(exp2f(sc[mi][tf][r] - mn[r]));
    }
    // ---- PV: acc += P·V, sums += P·1 ----
    #pragma unroll
    for (int kk=0;kk<2;kk++) {
      bf8 pa[2];
      #pragma unroll
      for (int mi=0;mi<2;mi++)
        pa[mi] = *(const bf8*)(Pl + (mi*16 + l15)*72 + kk*32 + l4*8);
      #pragma unroll
      for (int mi=0;mi<2;mi++) sums[mi] = MFMA16(pa[mi], ones, sums[mi]);
      #pragma unroll
      for (int cf=0;cf<8;cf++) {
        bf8 bv = *(const bf8*)(Vbase + (size_t)(cf*16 + l15)*SEQ + t0 + kk*32 + l4*8);
        #pragma unroll
        for (int mi=0;mi<2;mi++) acc[mi][cf] = MFMA16(pa[mi], bv, acc[mi][cf]);
      }
    }
  }
  #pragma unroll
  for (int mi=0;mi<2;mi++) {
    float inv[4];
    #pragma unroll
    for (int r=0;r<4;r++) inv[r] = 1.0f / sums[mi][r];
    #pragma unroll
    for (int cf=0;cf<8;cf++)
      #pragma unroll
      for (int r=0;r<4;r++) {
        size_t m = rowbase + mi*16 + l4*4 + r;
        vlat[m*NKV + hh*128 + cf*16 + l15] = f2b(acc[mi][cf][r] * inv[r]);
      }
  }
}

extern "C" void kernel_launch(void* const* d_in, const int* in_sizes, int n_in,
                              void* d_out, int out_size, void* d_ws, size_t ws_size,
                              hipStream_t stream) {
  const float* h     = (const float*)d_in[0];
  const float* wqaw  = (const float*)d_in[2];
  const float* wqa_b = (const float*)d_in[3];
  const float* qnw   = (const float*)d_in[4];
  const float* wqbw  = (const float*)d_in[5];
  const float* wqbb  = (const float*)d_in[6];
  const float* wkvaw = (const float*)d_in[7];
  const float* wkva_b= (const float*)d_in[8];
  const float* kvnw  = (const float*)d_in[9];
  const float* wkvb  = (const float*)d_in[10];
  const float* wow   = (const float*)d_in[11];
  const float* wob   = (const float*)d_in[12];

  char* ws = (char*)d_ws;
  size_t off = 0;
  auto alloc = [&](size_t bytes) { char* p = ws + off; off += (bytes + 255) & ~(size_t)255; return p; };
  short* hb     = (short*)alloc((size_t)MR*DM*2);
  short* wqab16 = (short*)alloc((size_t)DLQ*DM*2);
  short* wkvab16= (short*)alloc((size_t)DLKV*DM*2);
  short* qlat   = (short*)alloc((size_t)MR*DLQ*2);
  short* kvnb   = (short*)alloc((size_t)MR*DLKV*2);
  short* kvnT   = (short*)alloc((size_t)MR*DLKV*2);
  short* Wc     = (short*)alloc((size_t)NKV*DLQ*2);
  float* bc     = (float*)alloc((size_t)NKV*4);
  short* qkv    = (short*)alloc((size_t)MR*NKV*2);
  short* vlat   = (short*)alloc((size_t)MR*NKV*2);
  short* W2     = (short*)alloc((size_t)DM*NKV*2);

  k_conv<<<2048, 256, 0, stream>>>(h, wqaw, wkvaw, hb, wqab16, wkvab16);
  k_wcomb<<<NKV, 256, 0, stream>>>(wqbw, wqbb, wkvb, Wc, bc);
  k_w2<<<(DM*NKV)/256, 256, 0, stream>>>(wow, wkvb, W2);
  k_proj_rms<DLQ,  false><<<MR/32, 256, 0, stream>>>(hb, wqab16,  wqa_b,  qnw,  qlat, nullptr);
  k_proj_rms<DLKV, true ><<<MR/32, 256, 0, stream>>>(hb, wkvab16, wkva_b, kvnw, kvnb, kvnT);
  k_gemm<true ><<<dim3(NKV/128, MR/128), 256, 0, stream>>>(qlat, Wc, bc, qkv, NKV, DLQ);
  k_flash<<<dim3(64, 64), 64, 0, stream>>>(qkv, kvnb, kvnT, vlat);
  k_gemm<false><<<dim3(DM/128, MR/128), 256, 0, stream>>>(vlat, W2, wob, d_out, DM, NKV);
}

// Round 3
// 412.992 us; speedup vs baseline: 1.6475x; 1.2054x over previous
//
#include <hip/hip_runtime.h>
#include <stdint.h>

#define NB 4
#define SEQ 2048
#define DM 1024
#define NH 16
#define NDQK 20
#define NDV 64
#define DLQ 256
#define DLKV 128
#define MR (NB*SEQ)       // 8192 rows
#define NKV (NH*DLKV)     // 2048

typedef __attribute__((ext_vector_type(8))) short bf8;   // 8 bf16 (4 VGPR) MFMA A/B frag
typedef __attribute__((ext_vector_type(4))) float f4;    // MFMA C/D frag
typedef __attribute__((ext_vector_type(4))) short s4;

#define MFMA16(a,b,c) __builtin_amdgcn_mfma_f32_16x16x32_bf16(a, b, c, 0, 0, 0)

__device__ __forceinline__ short f2b(float f) {  // f32 -> bf16 RNE
  union { float f; unsigned u; } v; v.f = f;
  return (short)((v.u + 0x7FFFu + ((v.u >> 16) & 1u)) >> 16);
}

__device__ __forceinline__ void gld16(void* lds, const void* g) {
  __builtin_amdgcn_global_load_lds((const __attribute__((address_space(1))) void*)g,
                                   (__attribute__((address_space(3))) void*)lds, 16, 0, 0);
}

// 16-lane max reduce on the VALU pipe (DPP), not LDS (shfl_xor = ds_swizzle).
__device__ __forceinline__ float dppmax16(float v) {
  int t;
  t = __builtin_amdgcn_update_dpp(0, __float_as_int(v), 0xB1,  0xF, 0xF, true); v = fmaxf(v, __int_as_float(t)); // quad_perm 1,0,3,2
  t = __builtin_amdgcn_update_dpp(0, __float_as_int(v), 0x4E,  0xF, 0xF, true); v = fmaxf(v, __int_as_float(t)); // quad_perm 2,3,0,1
  t = __builtin_amdgcn_update_dpp(0, __float_as_int(v), 0x141, 0xF, 0xF, true); v = fmaxf(v, __int_as_float(t)); // row_half_mirror
  t = __builtin_amdgcn_update_dpp(0, __float_as_int(v), 0x140, 0xF, 0xF, true); v = fmaxf(v, __int_as_float(t)); // row_mirror
  return v;
}

// ---------------- convert h / wq_a / wkv_a to bf16 ----------------
__global__ __launch_bounds__(256) void k_conv(const float* __restrict__ h,
    const float* __restrict__ wqa, const float* __restrict__ wkva,
    short* __restrict__ hb, short* __restrict__ wqab, short* __restrict__ wkvab) {
  const int NH4 = (MR*DM)/4, NQ4 = (DLQ*DM)/4, NK4 = (DLKV*DM)/4;
  int stride = gridDim.x * blockDim.x;
  for (int i = blockIdx.x*blockDim.x + threadIdx.x; i < NH4+NQ4+NK4; i += stride) {
    const float4* s; short* d; int o;
    if (i < NH4)            { s = (const float4*)h;    d = hb;     o = i; }
    else if (i < NH4+NQ4)   { s = (const float4*)wqa;  d = wqab;   o = i - NH4; }
    else                    { s = (const float4*)wkva; d = wkvab;  o = i - NH4 - NQ4; }
    float4 v = s[o];
    s4 r; r.x = f2b(v.x); r.y = f2b(v.y); r.z = f2b(v.z); r.w = f2b(v.w);
    *(s4*)(d + (size_t)o*4) = r;
  }
}

// ---------------- Wcomb[h*128+c][l] = scale*log2e * sum_q wq_b[h*20+q][l]*wkv_b[h][q][c] ----------------
__global__ __launch_bounds__(256) void k_wcomb(const float* __restrict__ wqbw,
    const float* __restrict__ wqbb, const float* __restrict__ wkvb,
    short* __restrict__ Wc, float* __restrict__ bc) {
  const float SC = 0.22360679774997896f * 1.4426950408889634f; // DQK^-0.5 * log2(e)
  int n = blockIdx.x, l = threadIdx.x;
  int hh = n >> 7, c = n & 127;
  float acc = 0.f, bacc = 0.f;
  for (int q = 0; q < NDQK; ++q) {
    float wv = wkvb[(hh*84 + q)*128 + c];
    acc  += wqbw[(hh*20 + q)*256 + l] * wv;
    bacc += wqbb[hh*20 + q] * wv;
  }
  Wc[(size_t)n*256 + l] = f2b(acc * SC);
  if (l == 0) bc[n] = bacc * SC;
}

// ---------------- W2[d][h*128+c] = sum_v wo[d][h*64+v]*wkv_b[h][20+v][c] ----------------
__global__ __launch_bounds__(256) void k_w2(const float* __restrict__ wo,
    const float* __restrict__ wkvb, short* __restrict__ W2) {
  int idx = blockIdx.x*256 + threadIdx.x;
  int d = idx >> 11, k = idx & 2047, hh = k >> 7, c = k & 127;
  float acc = 0.f;
  #pragma unroll 8
  for (int v = 0; v < NDV; ++v)
    acc += wo[d*1024 + hh*64 + v] * wkvb[(hh*84 + 20 + v)*128 + c];
  W2[idx] = f2b(acc);
}

// ---------------- fused latent projection + RMSnorm ----------------
template<int BN, bool WT>
__global__ __launch_bounds__(256) void k_proj_rms(const short* __restrict__ Ab,
    const short* __restrict__ Wb, const float* __restrict__ bias,
    const float* __restrict__ nw, short* __restrict__ outp, short* __restrict__ outT) {
  constexpr int WN = BN/4, NI = WN/16;
  __shared__ __align__(16) char As[32*128];
  __shared__ __align__(16) char Ws[BN*128];
  __shared__ float red[32][4];
  const int tid = threadIdx.x, l = tid & 63, w = tid >> 6;
  const int l15 = l & 15, l4 = l >> 4, l7 = l & 7, l3 = l >> 3;
  const int m0 = blockIdx.x * 32;
  f4 z = {0.f,0.f,0.f,0.f};
  f4 acc[2][NI];
  for (int mi=0;mi<2;mi++) for (int ni=0;ni<NI;ni++) acc[mi][ni] = z;
  for (int kt = 0; kt < DM/64; ++kt) {
    __syncthreads();
    { int row = w*8 + l3;
      gld16(As + w*1024 + l*16,
            (const char*)Ab + ((size_t)(m0+row)*DM + kt*64)*2 + ((l7 ^ (row&7))*16)); }
    #pragma unroll
    for (int i = 0; i < BN/32; ++i) {
      int ci = w*(BN/32) + i, row = ci*8 + l3;
      gld16(Ws + ci*1024 + l*16,
            (const char*)Wb + ((size_t)row*DM + kt*64)*2 + ((l7 ^ (row&7))*16));
    }
    asm volatile("s_waitcnt vmcnt(0)" ::: "memory");
    __syncthreads();
    #pragma unroll
    for (int kk = 0; kk < 2; ++kk) {
      bf8 a[2], bb[NI];
      #pragma unroll
      for (int mi=0;mi<2;mi++) { int row = mi*16 + l15;
        a[mi] = *(const bf8*)(As + row*128 + ((kk*64 + l4*16) ^ ((row&7)<<4))); }
      #pragma unroll
      for (int ni=0;ni<NI;ni++) { int n = w*WN + ni*16 + l15;
        bb[ni] = *(const bf8*)(Ws + n*128 + ((kk*64 + l4*16) ^ ((n&7)<<4))); }
      #pragma unroll
      for (int mi=0;mi<2;mi++)
        #pragma unroll
        for (int ni=0;ni<NI;ni++) acc[mi][ni] = MFMA16(a[mi], bb[ni], acc[mi][ni]);
    }
  }
  float bn[NI], nwv[NI];
  #pragma unroll
  for (int ni=0;ni<NI;ni++) { int n = w*WN + ni*16 + l15; bn[ni] = bias[n]; nwv[ni] = nw[n]; }
  #pragma unroll
  for (int mi=0;mi<2;mi++) {
    f4 v = z;
    #pragma unroll
    for (int ni=0;ni<NI;ni++)
      #pragma unroll
      for (int r=0;r<4;r++) { acc[mi][ni][r] += bn[ni]; v[r] += acc[mi][ni][r]*acc[mi][ni][r]; }
    #pragma unroll
    for (int r=0;r<4;r++)
      for (int x=1;x<16;x<<=1) v[r] += __shfl_xor(v[r], x);
    if (l15 == 0) {
      #pragma unroll
      for (int r=0;r<4;r++) red[mi*16 + l4*4 + r][w] = v[r];
    }
  }
  __syncthreads();
  #pragma unroll
  for (int mi=0;mi<2;mi++) {
    float sc[4];
    #pragma unroll
    for (int r=0;r<4;r++) { int row = mi*16 + l4*4 + r;
      float t = red[row][0] + red[row][1] + red[row][2] + red[row][3];
      sc[r] = rsqrtf(t * (1.0f/BN) + 1e-6f); }
    #pragma unroll
    for (int ni=0;ni<NI;ni++) { int n = w*WN + ni*16 + l15;
      #pragma unroll
      for (int r=0;r<4;r++) {
        int m = m0 + mi*16 + l4*4 + r;
        short bv = f2b(acc[mi][ni][r] * sc[r] * nwv[ni]);
        outp[(size_t)m*BN + n] = bv;
        if (WT) { int bb2 = m >> 11, s = m & 2047;
                  outT[((size_t)bb2*DLKV + n)*SEQ + s] = bv; }
      }
    }
  }
}

// ---------------- GEMM C[m][n] = A[m]·W[n] (+bias): BM=BN=128, BK=64, 4 waves ----------------
template<bool BOUT>
__global__ __launch_bounds__(256) void k_gemm(const short* __restrict__ A,
    const short* __restrict__ W, const float* __restrict__ bias,
    void* __restrict__ outp, int N, int K) {
  __shared__ __align__(16) char As[128*128];
  __shared__ __align__(16) char Ws[128*128];
  const int tid = threadIdx.x, l = tid & 63, w = tid >> 6;
  const int l15 = l&15, l4 = l>>4, l7 = l&7, l3 = l>>3;
  const int wm = w >> 1, wn = w & 1;
  const int n0 = blockIdx.x * 128, m0 = blockIdx.y * 128;
  f4 z = {0.f,0.f,0.f,0.f};
  f4 acc[4][4];
  for (int mi=0;mi<4;mi++) for (int ni=0;ni<4;ni++) acc[mi][ni] = z;
  for (int kt = 0; kt < (K>>6); ++kt) {
    __syncthreads();
    #pragma unroll
    for (int i=0;i<4;i++) {
      int ci = w*4 + i, row = ci*8 + l3;
      gld16(As + ci*1024 + l*16,
            (const char*)A + ((size_t)(m0+row)*K + kt*64)*2 + ((l7^(row&7))*16));
      gld16(Ws + ci*1024 + l*16,
            (const char*)W + ((size_t)(n0+row)*K + kt*64)*2 + ((l7^(row&7))*16));
    }
    asm volatile("s_waitcnt vmcnt(0)" ::: "memory");
    __syncthreads();
    #pragma unroll
    for (int kk=0;kk<2;kk++) {
      bf8 a[4], bb[4];
      #pragma unroll
      for (int mi=0;mi<4;mi++) { int row = wm*64+mi*16+l15;
        a[mi] = *(const bf8*)(As + row*128 + ((kk*64+l4*16)^((row&7)<<4))); }
      #pragma unroll
      for (int ni=0;ni<4;ni++) { int row = wn*64+ni*16+l15;
        bb[ni] = *(const bf8*)(Ws + row*128 + ((kk*64+l4*16)^((row&7)<<4))); }
      #pragma unroll
      for (int mi=0;mi<4;mi++)
        #pragma unroll
        for (int ni=0;ni<4;ni++) acc[mi][ni] = MFMA16(a[mi], bb[ni], acc[mi][ni]);
    }
  }
  #pragma unroll
  for (int ni=0;ni<4;ni++) {
    int n = n0 + wn*64 + ni*16 + l15;
    float bn = bias[n];
    #pragma unroll
    for (int mi=0;mi<4;mi++)
      #pragma unroll
      for (int r=0;r<4;r++) {
        int m = m0 + wm*64 + mi*16 + l4*4 + r;
        float val = acc[mi][ni][r] + bn;
        if (BOUT) ((short*)outp)[(size_t)m*N + n] = f2b(val);
        else      ((float*)outp)[(size_t)m*N + n] = val;
      }
  }
}

// ---------------- flash attention: 8 waves = 8 heads share latent K via LDS ----------------
// 256 blocks, XCD-pinned (blockIdx%8 -> XCD -> one batch), triangle-paired (y, 63-y).
// K: LDS double-buffered via global_load_lds + counted vmcnt(2). V: global-direct (L1-shared).
__global__ __launch_bounds__(512, 1) void k_flash(const short* __restrict__ qkv,
    const short* __restrict__ kvn, const short* __restrict__ kvnT,
    short* __restrict__ vlat) {
  __shared__ __align__(16) char Ks[2][64*256];   // K tile [t][c] bf16, xor-swizzled, dbuf
  __shared__ __align__(16) short Pl[8][32*72];   // per-wave P
  const int tid = threadIdx.x, l = tid & 63, w = tid >> 6;
  const int l15 = l & 15, l4 = l >> 4;
  const int id = blockIdx.x;
  const int b   = (id & 7) >> 1;                  // XCD (id%8) pinned to one batch
  const int hh  = (((id >> 3) & 1) << 3) | w;     // wave = head within 8-head group
  const int y   = ((id >> 4) << 1) | (id & 1);    // 0..31
  const int qbs0 = y, qbs1 = 63 - y;              // paired q-blocks: nt sums to 33
  const int ntA = (y >> 1) + 1, ntT = 33;
  const short* Kb = kvn  + (size_t)b*SEQ*DLKV;    // [t][c]
  const short* Vb = kvnT + (size_t)b*DLKV*SEQ;    // [c][t]
  short* Pw = Pl[w];

  const short ONE = 0x3F80;
  bf8 ones;
  #pragma unroll
  for (int j2=0;j2<8;j2++) ones[j2] = ONE;
  f4 z = {0.f,0.f,0.f,0.f};

  // ---- segment state (q-block A first) ----
  int qw = qbs0*32;
  size_t rowbase = (size_t)b*SEQ + qw;
  bf8 qf[2][4];
  f4 acc[2][8], sums[2]; float mr[2][4];
  #pragma unroll
  for (int mi=0;mi<2;mi++) {
    #pragma unroll
    for (int kk=0;kk<4;kk++)
      qf[mi][kk] = *(const bf8*)(qkv + (rowbase + mi*16 + l15)*NKV + hh*128 + kk*32 + l4*8);
    sums[mi] = z;
    #pragma unroll
    for (int cf=0;cf<8;cf++) acc[mi][cf] = z;
    #pragma unroll
    for (int r=0;r<4;r++) mr[mi][r] = -3.0e38f;
  }

  // prologue: stage tile 0 into buf 0 (1024 16B chunks, 2 per thread)
  #pragma unroll
  for (int r=0;r<2;r++) {
    int ci = r*512 + tid, row = ci >> 4, c16 = ci & 15;
    gld16(Ks[0] + ci*16, (const char*)Kb + row*256 + ((c16 ^ (row & 7))*16));
  }
  int cur = 0, t = 0;
  for (int j = 0; j < ntT; ++j) {
    // stage next tile (clamped; always 2 loads -> uniform vmcnt accounting)
    const int tn = (j+1 >= ntT) ? t : ((j+1 == ntA) ? 0 : t+1);
    {
      const char* src = (const char*)(Kb + (size_t)tn*64*DLKV);
      #pragma unroll
      for (int r=0;r<2;r++) {
        int ci = r*512 + tid, row = ci >> 4, c16 = ci & 15;
        gld16(Ks[cur^1] + ci*16, src + row*256 + ((c16 ^ (row & 7))*16));
      }
    }
    asm volatile("s_waitcnt vmcnt(2)" ::: "memory");  // current tile's 2 stage-loads done
    __syncthreads();
    const int t0 = t*64;
    const char* kb = Ks[cur];
    // ---- scores = Q·K^T (exp2 domain, pre-scaled) ----
    f4 sc[2][4];
    #pragma unroll
    for (int mi=0;mi<2;mi++)
      #pragma unroll
      for (int tf=0;tf<4;tf++) sc[mi][tf] = z;
    #pragma unroll
    for (int kk=0;kk<4;kk++) {
      bf8 bk[4];
      #pragma unroll
      for (int tf=0;tf<4;tf++) { int tt = tf*16 + l15;
        bk[tf] = *(const bf8*)(kb + tt*256 + ((kk*64 + l4*16) ^ ((tt&7)<<4))); }
      #pragma unroll
      for (int mi=0;mi<2;mi++)
        #pragma unroll
        for (int tf=0;tf<4;tf++) sc[mi][tf] = MFMA16(qf[mi][kk], bk[tf], sc[mi][tf]);
    }
    // V prefetch (first half) — hides under softmax
    bf8 vr0[8], vr1[8];
    #pragma unroll
    for (int cf=0;cf<8;cf++)
      vr0[cf] = *(const bf8*)(Vb + (size_t)(cf*16 + l15)*SEQ + t0 + l4*8);
    if (t0 + 63 > qw) {   // diagonal: causal mask
      #pragma unroll
      for (int mi=0;mi<2;mi++)
        #pragma unroll
        for (int tf=0;tf<4;tf++)
          #pragma unroll
          for (int r=0;r<4;r++) {
            int qg = qw + mi*16 + l4*4 + r, tg = t0 + tf*16 + l15;
            if (tg > qg) sc[mi][tf][r] = -3.0e38f;
          }
    }
    // ---- online softmax: DPP max (VALU), P -> LDS, sums via ones-MFMA ----
    #pragma unroll
    for (int mi=0;mi<2;mi++) {
      float mn[4], al[4];
      #pragma unroll
      for (int r=0;r<4;r++) {
        float v = fmaxf(fmaxf(sc[mi][0][r], sc[mi][1][r]), fmaxf(sc[mi][2][r], sc[mi][3][r]));
        v = dppmax16(v);
        float m2 = fmaxf(mr[mi][r], v);
        al[r] = exp2f(mr[mi][r] - m2);
        mr[mi][r] = m2; mn[r] = m2;
      }
      #pragma unroll
      for (int r=0;r<4;r++) { sums[mi][r] *= al[r];
        #pragma unroll
        for (int cf=0;cf<8;cf++) acc[mi][cf][r] *= al[r]; }
      #pragma unroll
      for (int tf=0;tf<4;tf++)
        #pragma unroll
        for (int r=0;r<4;r++)
          Pw[(mi*16 + l4*4 + r)*72 + tf*16 + l15] = f2b(exp2f(sc[mi][tf][r] - mn[r]));
    }
    // V prefetch (second half)
    #pragma unroll
    for (int cf=0;cf<8;cf++)
      vr1[cf] = *(const bf8*)(Vb + (size_t)(cf*16 + l15)*SEQ + t0 + 32 + l4*8);
    // ---- PV: acc += P·V, sums += P·1 ----
    #pragma unroll
    for (int kk=0;kk<2;kk++) {
      bf8 pa[2];
      #pragma unroll
      for (int mi=0;mi<2;mi++)
        pa[mi] = *(const bf8*)(Pw + (mi*16 + l15)*72 + kk*32 + l4*8);
      #pragma unroll
      for (int mi=0;mi<2;mi++) sums[mi] = MFMA16(pa[mi], ones, sums[mi]);
      #pragma unroll
      for (int cf=0;cf<8;cf++) {
        bf8 bv = kk ? vr1[cf] : vr0[cf];
        #pragma unroll
        for (int mi=0;mi<2;mi++) acc[mi][cf] = MFMA16(pa[mi], bv, acc[mi][cf]);
      }
    }
    __syncthreads();   // protect Ks[cur] (read above) from next iteration's staging
    cur ^= 1;
    // ---- segment boundary: write out, reinit for q-block B ----
    if (j+1 == ntA || j+1 == ntT) {
      #pragma unroll
      for (int mi=0;mi<2;mi++) {
        float inv[4];
        #pragma unroll
        for (int r=0;r<4;r++) inv[r] = 1.0f / sums[mi][r];
        #pragma unroll
        for (int cf=0;cf<8;cf++)
          #pragma unroll
          for (int r=0;r<4;r++) {
            size_t m = rowbase + mi*16 + l4*4 + r;
            vlat[m*NKV + hh*128 + cf*16 + l15] = f2b(acc[mi][cf][r] * inv[r]);
          }
      }
      if (j+1 == ntA) {
        qw = qbs1*32; rowbase = (size_t)b*SEQ + qw;
        #pragma unroll
        for (int mi=0;mi<2;mi++) {
          #pragma unroll
          for (int kk=0;kk<4;kk++)
            qf[mi][kk] = *(const bf8*)(qkv + (rowbase + mi*16 + l15)*NKV + hh*128 + kk*32 + l4*8);
          sums[mi] = z;
          #pragma unroll
          for (int cf=0;cf<8;cf++) acc[mi][cf] = z;
          #pragma unroll
          for (int r=0;r<4;r++) mr[mi][r] = -3.0e38f;
        }
      }
    }
    t = tn;
  }
}

extern "C" void kernel_launch(void* const* d_in, const int* in_sizes, int n_in,
                              void* d_out, int out_size, void* d_ws, size_t ws_size,
                              hipStream_t stream) {
  const float* h     = (const float*)d_in[0];
  const float* wqaw  = (const float*)d_in[2];
  const float* wqa_b = (const float*)d_in[3];
  const float* qnw   = (const float*)d_in[4];
  const float* wqbw  = (const float*)d_in[5];
  const float* wqbb  = (const float*)d_in[6];
  const float* wkvaw = (const float*)d_in[7];
  const float* wkva_b= (const float*)d_in[8];
  const float* kvnw  = (const float*)d_in[9];
  const float* wkvb  = (const float*)d_in[10];
  const float* wow   = (const float*)d_in[11];
  const float* wob   = (const float*)d_in[12];

  char* ws = (char*)d_ws;
  size_t off = 0;
  auto alloc = [&](size_t bytes) { char* p = ws + off; off += (bytes + 255) & ~(size_t)255; return p; };
  short* hb     = (short*)alloc((size_t)MR*DM*2);
  short* wqab16 = (short*)alloc((size_t)DLQ*DM*2);
  short* wkvab16= (short*)alloc((size_t)DLKV*DM*2);
  short* qlat   = (short*)alloc((size_t)MR*DLQ*2);
  short* kvnb   = (short*)alloc((size_t)MR*DLKV*2);
  short* kvnT   = (short*)alloc((size_t)MR*DLKV*2);
  short* Wc     = (short*)alloc((size_t)NKV*DLQ*2);
  float* bc     = (float*)alloc((size_t)NKV*4);
  short* qkv    = (short*)alloc((size_t)MR*NKV*2);
  short* vlat   = (short*)alloc((size_t)MR*NKV*2);
  short* W2     = (short*)alloc((size_t)DM*NKV*2);

  k_conv<<<2048, 256, 0, stream>>>(h, wqaw, wkvaw, hb, wqab16, wkvab16);
  k_wcomb<<<NKV, 256, 0, stream>>>(wqbw, wqbb, wkvb, Wc, bc);
  k_w2<<<(DM*NKV)/256, 256, 0, stream>>>(wow, wkvb, W2);
  k_proj_rms<DLQ,  false><<<MR/32, 256, 0, stream>>>(hb, wqab16,  wqa_b,  qnw,  qlat, nullptr);
  k_proj_rms<DLKV, true ><<<MR/32, 256, 0, stream>>>(hb, wkvab16, wkva_b, kvnw, kvnb, kvnT);
  k_gemm<true ><<<dim3(NKV/128, MR/128), 256, 0, stream>>>(qlat, Wc, bc, qkv, NKV, DLQ);
  k_flash<<<256, 512, 0, stream>>>(qkv, kvnb, kvnT, vlat);
  k_gemm<false><<<dim3(DM/128, MR/128), 256, 0, stream>>>(vlat, W2, wob, d_out, DM, NKV);
}